// Round 9
// baseline (499.835 us; speedup 1.0000x reference)
//
#include <hip/hip_runtime.h>

// ---------------------------------------------------------------------------
// StochasticKeyNet:  decode_i(relu(encode_i(y))) == relu(y)  (diag > 0), so
// only the first decode and last encode survive.  Convs = implicit-GEMM f16
// MFMA (16x16x32), activations packed [ci/8][h][w][n][ci%8] f16.
// R8: l1/l3/l4 use global_load_lds (async DMA->LDS, no VGPR round trip),
// double-buffered, loads for c+1 issued post-barrier so the next barrier's
// vmcnt drain is covered by compute(c).  Block = 2 pixels x CB co-waves:
// A+B staged once per block.  All other layers: R6 direct-load path (known
// good, 330us).
// ---------------------------------------------------------------------------

#define B 128
#define ZPAD 2048   // leading zero page (elements) in each packed act buffer

typedef _Float16 f16_t;
typedef __attribute__((ext_vector_type(8))) _Float16 f16x8;
typedef __attribute__((ext_vector_type(4))) _Float16 f16x4;
typedef __attribute__((ext_vector_type(4))) float f32x4;

__device__ __forceinline__ void async_copy16(const f16_t* g, char* l) {
    __builtin_amdgcn_global_load_lds(
        (const __attribute__((address_space(1))) void*)g,
        (__attribute__((address_space(3))) void*)l,
        16, 0, 0);
}

// ---------------- fp32 helpers ----------------------------------------------

__global__ void decode_kernel(const float* __restrict__ x, const int* __restrict__ perm,
                              const float* __restrict__ diag, float* __restrict__ v, int nrows) {
    int row = blockIdx.x * 8 + (threadIdx.x >> 5);
    if (row >= nrows) return;
    int lane = threadIdx.x & 31;
    int p = perm[row];
    float inv = 1.0f / diag[row];
    float4 val = ((const float4*)(x + (size_t)row * B))[lane];
    val.x *= inv; val.y *= inv; val.z *= inv; val.w *= inv;
    ((float4*)(v + (size_t)p * B))[lane] = val;
}

__global__ void fc_kernel(const float* __restrict__ v, const float* __restrict__ w,
                          const float* __restrict__ b, float* __restrict__ y,
                          int K, int R, int do_relu) {
    int r = blockIdx.x;
    int n = threadIdx.x;
    float t = v[(size_t)K * B + n];
    float val;
    if (r == R) {
        val = t;
    } else {
        float a0 = 0.f, a1 = 0.f, a2 = 0.f, a3 = 0.f;
        float a4 = 0.f, a5 = 0.f, a6 = 0.f, a7 = 0.f;
        const float* wr = w + (size_t)r * K;
        int k = 0;
        for (; k + 8 <= K; k += 8) {
            float4 w0 = *(const float4*)(wr + k);
            float4 w1 = *(const float4*)(wr + k + 4);
            float x0 = v[(size_t)(k + 0) * B + n];
            float x1 = v[(size_t)(k + 1) * B + n];
            float x2 = v[(size_t)(k + 2) * B + n];
            float x3 = v[(size_t)(k + 3) * B + n];
            float x4 = v[(size_t)(k + 4) * B + n];
            float x5 = v[(size_t)(k + 5) * B + n];
            float x6 = v[(size_t)(k + 6) * B + n];
            float x7 = v[(size_t)(k + 7) * B + n];
            a0 = fmaf(w0.x, x0, a0);
            a1 = fmaf(w0.y, x1, a1);
            a2 = fmaf(w0.z, x2, a2);
            a3 = fmaf(w0.w, x3, a3);
            a4 = fmaf(w1.x, x4, a4);
            a5 = fmaf(w1.y, x5, a5);
            a6 = fmaf(w1.z, x6, a6);
            a7 = fmaf(w1.w, x7, a7);
        }
        for (; k < K; ++k)
            a0 = fmaf(wr[k], v[(size_t)k * B + n], a0);
        val = b[r] * t + ((a0 + a1) + (a2 + a3)) + ((a4 + a5) + (a6 + a7));
    }
    if (do_relu) val = fmaxf(val, 0.f);
    y[(size_t)r * B + n] = val;
}

// fc2 + final encode fused
__global__ void fc2_encode_kernel(const float* __restrict__ v, const float* __restrict__ w,
                                  const float* __restrict__ b, const int* __restrict__ perm,
                                  const float* __restrict__ diag, float* __restrict__ out) {
    int jrow = blockIdx.x;          // 0..10
    int n = threadIdx.x;            // 0..127
    int r = perm[jrow];
    float d = diag[jrow];
    float t = v[100 * B + n];
    float val;
    if (r == 10) {
        val = t;
    } else {
        float a0 = 0.f, a1 = 0.f, a2 = 0.f, a3 = 0.f;
        const float* wr = w + (size_t)r * 100;
        for (int k = 0; k < 100; k += 4) {
            float4 w4 = *(const float4*)(wr + k);
            a0 = fmaf(w4.x, v[(size_t)(k + 0) * B + n], a0);
            a1 = fmaf(w4.y, v[(size_t)(k + 1) * B + n], a1);
            a2 = fmaf(w4.z, v[(size_t)(k + 2) * B + n], a2);
            a3 = fmaf(w4.w, v[(size_t)(k + 3) * B + n], a3);
        }
        val = b[r] * t + (a0 + a1) + (a2 + a3);
    }
    out[(size_t)jrow * B + n] = d * val;
}

// ---------------- prep: pack decoded input to f16 [cg][p][n][8] -------------

__global__ void pack_input_kernel(const float* __restrict__ v, f16_t* __restrict__ xout,
                                  float* __restrict__ tout) {
    int idx = blockIdx.x * 256 + threadIdx.x;   // 1024*128 threads
    int p = idx >> 7, n = idx & 127;
    f16x8 o = {};
    o[0] = (f16_t)v[(size_t)(0 * 1024 + p) * B + n];
    o[1] = (f16_t)v[(size_t)(1 * 1024 + p) * B + n];
    o[2] = (f16_t)v[(size_t)(2 * 1024 + p) * B + n];
    *(f16x8*)(xout + ZPAD + (size_t)p * 1024 + n * 8) = o;
    if (idx < B) tout[idx] = v[(size_t)3072 * B + idx];
}

// ---------------- prep: pack all conv weights/biases to f16 -----------------

struct WArgs {
    const float* w[9]; const float* b[9];
    int Ci[9], Co[9], KS[9], Cp[9], NCG[9];
    int woff[10]; int boff[10];
};

__global__ void pack_weights_kernel(WArgs A, f16_t* __restrict__ wp, float* __restrict__ bp,
                                    f16_t* __restrict__ x8a, f16_t* __restrict__ x8b) {
    int idx = blockIdx.x * 256 + threadIdx.x;
    if (idx < ZPAD) { x8a[idx] = (f16_t)0.f; x8b[idx] = (f16_t)0.f; }
    if (idx < A.boff[9]) {
        int l = 0;
        while (idx >= A.boff[l + 1]) ++l;
        int co = idx - A.boff[l];
        bp[idx] = (co < A.Co[l]) ? A.b[l][co] : 0.f;
    }
    if (idx >= A.woff[9]) return;
    int l = 0;
    while (idx >= A.woff[l + 1]) ++l;
    int e = idx - A.woff[l];
    int j = e & 7;
    int t1 = e >> 3;
    int Cp = A.Cp[l];
    int co = t1 % Cp;
    int gg = t1 / Cp;
    int ncg = A.NCG[l];
    int tap = gg / ncg, cg = gg - tap * ncg;
    int ks = A.KS[l];
    int kh = tap / ks, kw = tap - kh * ks;
    int ci = cg * 8 + j;
    float val = 0.f;
    if (co < A.Co[l] && tap < ks * ks && ci < A.Ci[l])
        val = A.w[l][(((size_t)co * A.Ci[l] + ci) * ks + kh) * ks + kw];
    wp[idx] = (f16_t)val;
}

// ---------------- async-LDS MFMA conv (l1/l3/l4, KS=3, f16 out) -------------
// Block = PX pixels x COG co-waves.  Per chunk: waves issue global_load_lds
// (16B/lane, 1KB pieces) for chunk c+1 right after the barrier, then compute
// chunk c from the other LDS buffer.  The barrier's vmcnt drain for c+1 is
// covered by compute(c).  A staged once per block; B once per pixel.

template <int NS, int NSPLIT, int PX, int COG, int CP>
__global__ __launch_bounds__(64 * PX * COG, (PX * COG == 4) ? 2 : 3)
void conv_async_kernel(
    const f16_t* __restrict__ xin, const float* __restrict__ t_in,
    const f16_t* __restrict__ wp, const float* __restrict__ bp,
    f16_t* __restrict__ xout, float* __restrict__ t_out,
    int Hi, int Wi, int Wo_log2, int HWo, int stride, int pad,
    int NCG, int nchunk, int KGr, int Co, int PPB8)
{
    constexpr int W = PX * COG;
    constexpr int AP = CP / 16;                 // A 1KB pieces per chunk
    constexpr int NSP = NS / 4;                 // 1KB pieces per B slab
    constexpr int BP = PX * 4 * NSP;
    constexpr int NP = AP + BP;
    constexpr int ABYTES = CP * 64;
    constexpr int BUFSZ = ABYTES + BP * 1024;
    constexpr int MS = 4;

    __shared__ char smem[2 * BUFSZ];

    const int wave = threadIdx.x >> 6;
    const int lane = threadIdx.x & 63;
    const int q = lane >> 4;
    const int r = lane & 15;
    const int px_me = wave / COG;
    const int cg_me = wave - px_me * COG;
    const int co0 = cg_me * 64;

    const int gb = blockIdx.x;
    const int xcd = gb & 7;
    int j = gb >> 3;
    int nh = 0;
    if (NSPLIT == 2) { nh = j & 1; j >>= 1; }
    const int pp = xcd * PPB8 + j;
    const int ncol0 = nh * (NS * 16);
    const int ncol8 = ncol0 * 8;

    const f16_t* xdata = xin + ZPAD;
    const int HiWi = Hi * Wi;

    int hbb[PX], wbb[PX];
#pragma unroll
    for (int px = 0; px < PX; ++px) {
        int p_ = pp * PX + px;
        int ho = p_ >> Wo_log2, wo = p_ & ((1 << Wo_log2) - 1);
        hbb[px] = ho * stride - pad;
        wbb[px] = wo * stride - pad;
    }
    const int p_me = pp * PX + px_me;

    float tv[NS];
#pragma unroll
    for (int ns = 0; ns < NS; ++ns) tv[ns] = t_in[ncol0 + ns * 16 + r];

    f32x4 acc[MS][NS];
#pragma unroll
    for (int ms = 0; ms < MS; ++ms) {
        float4 b4 = *(const float4*)(bp + co0 + ms * 16 + q * 4);
#pragma unroll
        for (int ns = 0; ns < NS; ++ns) {
            acc[ms][ns][0] = b4.x * tv[ns];
            acc[ms][ns][1] = b4.y * tv[ns];
            acc[ms][ns][2] = b4.z * tv[ns];
            acc[ms][ns][3] = b4.w * tv[ns];
        }
    }

    // per-k-group staging trackers (wave-uniform): G = 4c+k
    int g4[4], cg4[4], kh4[4], kw4[4];
#pragma unroll
    for (int k = 0; k < 4; ++k) { g4[k] = k; cg4[k] = k; kh4[k] = 0; kw4[k] = 0; }

    auto stage = [&](int cc) {
        const f16_t* abase = wp + (size_t)cc * (4 * CP * 8);
        const f16_t* slab[PX][4];
#pragma unroll
        for (int k = 0; k < 4; ++k) {
            bool gv = (g4[k] < KGr);
            int khk = kh4[k], kwk = kw4[k];
            int cgHW = cg4[k] * HiWi;
#pragma unroll
            for (int px = 0; px < PX; ++px) {
                int hi = hbb[px] + khk, wi = wbb[px] + kwk;
                bool v = gv & ((unsigned)hi < (unsigned)Hi) & ((unsigned)wi < (unsigned)Wi);
                int boff = (cgHW + hi * Wi + wi) << 10;
                slab[px][k] = xdata + (v ? boff : -ZPAD) + ncol8;
            }
        }
        char* base = smem + (cc & 1) * BUFSZ;
#pragma unroll
        for (int idx = wave; idx < NP; idx += W) {
            const f16_t* g;
            int loff;
            if (idx < AP) {
                g = abase + idx * 512;
                loff = idx * 1024;
            } else {
                int bi = idx - AP;                     // (px*4+k)*NSP + sub
                int sub = (NSP == 2) ? (bi & 1) : 0;
                int pk  = (NSP == 2) ? (bi >> 1) : bi;
                int px = pk >> 2, k = pk & 3;
                g = slab[px][k] + sub * 512;
                loff = ABYTES + bi * 1024;
            }
            async_copy16(g + lane * 8, base + loff);
        }
#pragma unroll
        for (int k = 0; k < 4; ++k) {                  // NCG >= 12: one wrap max
            g4[k] += 4; cg4[k] += 4;
            if (cg4[k] >= NCG) {
                cg4[k] -= NCG;
                ++kw4[k];
                if (kw4[k] == 3) { kw4[k] = 0; ++kh4[k]; }
            }
        }
    };

    auto comp = [&](int cc) {
        const char* base = smem + (cc & 1) * BUFSZ;
        f16x8 af[MS], bf[NS];
#pragma unroll
        for (int ms = 0; ms < MS; ++ms)
            af[ms] = *(const f16x8*)(base + (q * CP + co0 + ms * 16 + r) * 16);
#pragma unroll
        for (int ns = 0; ns < NS; ++ns)
            bf[ns] = *(const f16x8*)(base + ABYTES + (px_me * 4 + q) * (NSP * 1024) + (ns * 16 + r) * 16);
#pragma unroll
        for (int ms = 0; ms < MS; ++ms)
#pragma unroll
            for (int ns = 0; ns < NS; ++ns)
                acc[ms][ns] = __builtin_amdgcn_mfma_f32_16x16x32_f16(af[ms], bf[ns], acc[ms][ns], 0, 0, 0);
    };

    stage(0);
    for (int c = 0; c < nchunk; ++c) {
        __syncthreads();                 // drains loads(c); WAR-protects buffers
        if (c + 1 < nchunk) stage(c + 1);
        comp(c);
    }

#pragma unroll
    for (int ms = 0; ms < MS; ++ms) {
        int cob = co0 + ms * 16 + q * 4;
        if (cob < Co) {
            int off0 = ((cob >> 3) * HWo + p_me) * 1024 + (cob & 7) + ncol8 + r * 8;
#pragma unroll
            for (int ns = 0; ns < NS; ++ns) {
                f16x4 h;
                h[0] = (f16_t)fmaxf(acc[ms][ns][0], 0.f);
                h[1] = (f16_t)fmaxf(acc[ms][ns][1], 0.f);
                h[2] = (f16_t)fmaxf(acc[ms][ns][2], 0.f);
                h[3] = (f16_t)fmaxf(acc[ms][ns][3], 0.f);
                *(f16x4*)(xout + ZPAD + off0 + ns * 128) = h;
            }
        }
    }
    if (gb == 0) {
        for (int i = threadIdx.x; i < B; i += 64 * W)
            t_out[i] = fmaxf(t_in[i], 0.f);
    }
}

// ---------------- direct-load MFMA conv (R6, known good) --------------------

template <int KS, int NS, int NSPLIT, int CBW, bool F32OUT>
__global__ __launch_bounds__(64 * CBW) void conv_mfma_kernel(
    const f16_t* __restrict__ xin, const float* __restrict__ t_in,
    const f16_t* __restrict__ wp, const float* __restrict__ bp,
    f16_t* __restrict__ xout, float* __restrict__ t_out, float* __restrict__ f32out,
    int Hi, int Wi, int Wo_log2, int HWo,
    int stride, int pad, int NCG, int nchunk, int KGr, int Co, int Co_pad,
    int PB8, int CB)
{
    constexpr int PF = 2;
    constexpr int MS = 4;
    const int wave = threadIdx.x >> 6;
    const int lane = threadIdx.x & 63;
    const int q = lane >> 4;
    const int r = lane & 15;

    const int gb = blockIdx.x;
    const int xcd = gb & 7;
    int j = gb >> 3;
    int nh = 0, cog, p;
    if (CBW > 1) {
        cog = wave;
        p = xcd * PB8 + j;
    } else {
        if (NSPLIT == 2) { nh = j & 1; j >>= 1; }
        cog = j % CB;
        p = xcd * PB8 + j / CB;
    }
    const int co0 = cog * 64;
    const int ncol0 = nh * (NS * 16);
    const int ncol8 = ncol0 * 8;

    const int ho = p >> Wo_log2;
    const int wo = p & ((1 << Wo_log2) - 1);
    const f16_t* xdata = xin + ZPAD;

    float tv[NS];
#pragma unroll
    for (int ns = 0; ns < NS; ++ns) tv[ns] = t_in[ncol0 + ns * 16 + r];

    f32x4 acc[MS][NS];
#pragma unroll
    for (int ms = 0; ms < MS; ++ms) {
        float4 b4 = *(const float4*)(bp + co0 + ms * 16 + q * 4);
#pragma unroll
        for (int ns = 0; ns < NS; ++ns) {
            acc[ms][ns][0] = b4.x * tv[ns];
            acc[ms][ns][1] = b4.y * tv[ns];
            acc[ms][ns][2] = b4.z * tv[ns];
            acc[ms][ns][3] = b4.w * tv[ns];
        }
    }

    const int hb = ho * stride - pad, wb = wo * stride - pad;
    const int HiWi = Hi * Wi;
    const int HiWi4 = 4 * HiWi;
    const int NCGHW = NCG * HiWi;
    const int wend = wb + KS;

    int g = q, cg = q, hi = hb, wi = wb, cgHW;
    {
        while (cg >= NCG) { cg -= NCG; ++wi; if (wi == wend) { wi = wb; ++hi; } }
        cgHW = cg * HiWi;
    }

    f16x8 bf[PF][NS], af[PF][MS];

    auto advance = [&]() {
        g += 4; cg += 4; cgHW += HiWi4;
        if (NCG >= 4) {
            int c2 = cg - NCG;
            bool wrap = c2 >= 0;
            int wn = wi + 1;
            bool ww = wrap & (wn == wend);
            cg   = wrap ? c2 : cg;
            cgHW = wrap ? cgHW - NCGHW : cgHW;
            wi   = wrap ? (ww ? wb : wn) : wi;
            hi   = ww ? hi + 1 : hi;
        } else {
            while (cg >= NCG) { cg -= NCG; cgHW -= NCGHW; ++wi; if (wi == wend) { wi = wb; ++hi; } }
        }
    };
    auto loadB = [&](f16x8* b) {
        bool v = (g < KGr) & ((unsigned)hi < (unsigned)Hi) & ((unsigned)wi < (unsigned)Wi);
        int boff = (cgHW + hi * Wi + wi) << 10;
        const f16_t* bb = xdata + (v ? boff : -ZPAD) + ncol8 + r * 8;
#pragma unroll
        for (int ns = 0; ns < NS; ++ns) b[ns] = *(const f16x8*)(bb + ns * 128);
    };
    auto loadA = [&](f16x8* a, int c) {
        int ac = c < nchunk ? c : nchunk - 1;
        const f16_t* ap = wp + (((ac * 4 + q) * Co_pad) + co0 + r) * 8;
#pragma unroll
        for (int ms = 0; ms < MS; ++ms) a[ms] = *(const f16x8*)(ap + ms * 128);
    };
    auto domfma = [&](f16x8* a, f16x8* b) {
#pragma unroll
        for (int ms = 0; ms < MS; ++ms)
#pragma unroll
            for (int ns = 0; ns < NS; ++ns)
                acc[ms][ns] = __builtin_amdgcn_mfma_f32_16x16x32_f16(a[ms], b[ns], acc[ms][ns], 0, 0, 0);
    };

#pragma unroll
    for (int pf = 0; pf < PF; ++pf) { loadB(bf[pf]); loadA(af[pf], pf); advance(); }
    const int nck = ((nchunk + PF - 1) / PF) * PF;
    for (int c = 0; c < nck; c += PF) {
#pragma unroll
        for (int pf = 0; pf < PF; ++pf) {
            domfma(af[pf], bf[pf]);
            loadB(bf[pf]); loadA(af[pf], c + PF + pf); advance();
        }
    }

    if (!F32OUT) {
#pragma unroll
        for (int ms = 0; ms < MS; ++ms) {
            int cob = co0 + ms * 16 + q * 4;
            if (cob < Co) {
                int off0 = ((cob >> 3) * HWo + p) * 1024 + (cob & 7) + ncol8 + r * 8;
#pragma unroll
                for (int ns = 0; ns < NS; ++ns) {
                    f16x4 h;
                    h[0] = (f16_t)fmaxf(acc[ms][ns][0], 0.f);
                    h[1] = (f16_t)fmaxf(acc[ms][ns][1], 0.f);
                    h[2] = (f16_t)fmaxf(acc[ms][ns][2], 0.f);
                    h[3] = (f16_t)fmaxf(acc[ms][ns][3], 0.f);
                    *(f16x4*)(xout + ZPAD + off0 + ns * 128) = h;
                }
            }
        }
        if (gb == 0) {
            for (int i = threadIdx.x; i < B; i += 64 * CBW)
                t_out[i] = fmaxf(t_in[i], 0.f);
        }
    } else {
#pragma unroll
        for (int ms = 0; ms < MS; ++ms)
#pragma unroll
            for (int ns = 0; ns < NS; ++ns)
#pragma unroll
                for (int e = 0; e < 4; ++e) {
                    int co = co0 + ms * 16 + q * 4 + e;
                    if (co < Co)
                        f32out[((size_t)co * HWo + p) * B + ncol0 + ns * 16 + r] =
                            fmaxf(acc[ms][ns][e], 0.f);
                }
        if (gb == 0) {
            for (int i = threadIdx.x; i < B; i += 64 * CBW)
                f32out[(size_t)Co * HWo * B + i] = fmaxf(t_in[i], 0.f);
        }
    }
}

// ---------------------------------------------------------------------------

extern "C" void kernel_launch(void* const* d_in, const int* in_sizes, int n_in,
                              void* d_out, int out_size, void* d_ws, size_t ws_size,
                              hipStream_t stream) {
    const float* x0 = (const float*)d_in[0];
    const int*   perm[12];
    const float* diag[12];
    for (int i = 0; i < 12; ++i) {
        perm[i] = (const int*)d_in[1 + 2 * i];
        diag[i] = (const float*)d_in[2 + 2 * i];
    }
    const float* wts[9];
    const float* bia[9];
    for (int j = 0; j < 9; ++j) {
        wts[j] = (const float*)d_in[25 + 2 * j];
        bia[j] = (const float*)d_in[26 + 2 * j];
    }
    const float* fw1 = (const float*)d_in[43];
    const float* fb1 = (const float*)d_in[44];
    const float* fw2 = (const float*)d_in[45];
    const float* fb2 = (const float*)d_in[46];
    float* out = (float*)d_out;

    // ----- layer tables -----
    static const int CiA[9]  = {3, 96, 96, 96, 192, 192, 192, 192, 192};
    static const int CoA[9]  = {96, 96, 96, 192, 192, 192, 192, 192, 10};
    static const int KSA[9]  = {3, 3, 3, 3, 3, 3, 3, 1, 1};
    static const int CpA[9]  = {128, 128, 128, 192, 192, 192, 192, 192, 64};
    static const int NCGA[9] = {1, 12, 12, 12, 24, 24, 24, 24, 24};
    static const int KGRA[9] = {9, 108, 108, 108, 216, 216, 216, 24, 24};
    static const int NCHK[9] = {3, 27, 27, 27, 54, 54, 54, 6, 6};
    static const int HiA[9]  = {32, 32, 32, 16, 16, 16, 8, 8, 8};
    static const int WoL[9]  = {5, 5, 4, 4, 4, 3, 3, 3, 3};
    static const int HWoA[9] = {1024, 1024, 256, 256, 256, 64, 64, 64, 64};
    static const int STA[9]  = {1, 1, 2, 1, 1, 2, 1, 1, 1};
    static const int PDA[9]  = {1, 1, 1, 1, 1, 1, 1, 0, 0};

    // ----- workspace layout -----
    char* wsb = (char*)d_ws;
    const size_t BUF_F32  = 1574912;
    const size_t X8_BYTES = (size_t)(ZPAD + 12 * 1024 * 1024) * 2;
    float* bufA = (float*)wsb;
    float* bufB = (float*)(wsb + BUF_F32);
    f16_t* x8a  = (f16_t*)(wsb + 2 * BUF_F32);
    f16_t* x8b  = (f16_t*)(wsb + 2 * BUF_F32 + X8_BYTES);
    f16_t* wpb  = (f16_t*)(wsb + 2 * BUF_F32 + 2 * X8_BYTES);
    const size_t WP_BYTES = 2888704;
    float* bpb  = (float*)(wsb + 2 * BUF_F32 + 2 * X8_BYTES + WP_BYTES);
    float* t0   = (float*)((char*)bpb + 8192);
    float* t1   = t0 + 256;

    // ----- pack weights/bias + zero the zero-pages (every call) -----
    WArgs WA;
    int wo = 0, bo = 0;
    for (int l = 0; l < 9; ++l) {
        WA.w[l] = wts[l]; WA.b[l] = bia[l];
        WA.Ci[l] = CiA[l]; WA.Co[l] = CoA[l]; WA.KS[l] = KSA[l];
        WA.Cp[l] = CpA[l]; WA.NCG[l] = NCGA[l];
        WA.woff[l] = wo; wo += NCHK[l] * 4 * CpA[l] * 8;
        WA.boff[l] = bo; bo += CpA[l];
    }
    WA.woff[9] = wo; WA.boff[9] = bo;
    pack_weights_kernel<<<(wo + 255) / 256, 256, 0, stream>>>(WA, wpb, bpb, x8a, x8b);

    // ----- initial decode + pack -----
    decode_kernel<<<(3073 + 7) / 8, 256, 0, stream>>>(x0, perm[0], diag[0], bufA, 3073);
    pack_input_kernel<<<131072 / 256, 256, 0, stream>>>(bufA, x8a, t0);

    // ----- conv stack -----
    f16_t* xin = x8a; f16_t* xout = x8b;
    float* tin = t0;  float* tout = t1;
    for (int l = 0; l < 9; ++l) {
        const int PB8 = HWoA[l] / 8;
        const int CB = CpA[l] / 64;
        const f16_t* wpl = wpb + WA.woff[l];
        const float* bpl = bpb + WA.boff[l];
        if (l == 0) {           // Ci=3, K tiny: direct 2-wave blocks
            conv_mfma_kernel<3, 8, 1, 2, false><<<8 * PB8, 128, 0, stream>>>(
                xin, tin, wpl, bpl, xout, tout, nullptr,
                HiA[l], HiA[l], WoL[l], HWoA[l], STA[l], PDA[l],
                NCGA[l], NCHK[l], KGRA[l], CoA[l], CpA[l], PB8, CB);
        } else if (l == 1) {    // 96->96 @32x32: async-LDS, 2px x 2cog
            conv_async_kernel<8, 1, 2, 2, 128><<<8 * (HWoA[l] / 16), 256, 0, stream>>>(
                xin, tin, wpl, bpl, xout, tout,
                HiA[l], HiA[l], WoL[l], HWoA[l], STA[l], PDA[l],
                NCGA[l], NCHK[l], KGRA[l], CoA[l], HWoA[l] / 16);
        } else if (l == 2) {    // stride-2: direct 2-wave blocks
            conv_mfma_kernel<3, 8, 1, 2, false><<<8 * PB8, 128, 0, stream>>>(
                xin, tin, wpl, bpl, xout, tout, nullptr,
                HiA[l], HiA[l], WoL[l], HWoA[l], STA[l], PDA[l],
                NCGA[l], NCHK[l], KGRA[l], CoA[l], CpA[l], PB8, CB);
        } else if (l <= 4) {    // 192->192 @16x16: async-LDS, 2px x 3cog, n-split
            conv_async_kernel<4, 2, 2, 3, 192><<<8 * (HWoA[l] / 16) * 2, 384, 0, stream>>>(
                xin, tin, wpl, bpl, xout, tout,
                HiA[l], HiA[l], WoL[l], HWoA[l], STA[l], PDA[l],
                NCGA[l], NCHK[l], KGRA[l], CoA[l], HWoA[l] / 16);
        } else if (l <= 6) {    // 8x8 KS=3 tail: direct 1-wave
            conv_mfma_kernel<3, 4, 2, 1, false><<<8 * PB8 * CB * 2, 64, 0, stream>>>(
                xin, tin, wpl, bpl, xout, tout, nullptr,
                HiA[l], HiA[l], WoL[l], HWoA[l], STA[l], PDA[l],
                NCGA[l], NCHK[l], KGRA[l], CoA[l], CpA[l], PB8, CB);
        } else if (l == 7) {    // 1x1
            conv_mfma_kernel<1, 4, 2, 1, false><<<8 * PB8 * CB * 2, 64, 0, stream>>>(
                xin, tin, wpl, bpl, xout, tout, nullptr,
                HiA[l], HiA[l], WoL[l], HWoA[l], STA[l], PDA[l],
                NCGA[l], NCHK[l], KGRA[l], CoA[l], CpA[l], PB8, CB);
        } else {                // last conv, fp32 out
            conv_mfma_kernel<1, 4, 2, 1, true><<<8 * PB8 * CB * 2, 64, 0, stream>>>(
                xin, tin, wpl, bpl, nullptr, nullptr, bufA,
                HiA[l], HiA[l], WoL[l], HWoA[l], STA[l], PDA[l],
                NCGA[l], NCHK[l], KGRA[l], CoA[l], CpA[l], PB8, CB);
        }
        f16_t* xt = xin; xin = xout; xout = xt;
        float* tt = tin; tin = tout; tout = tt;
    }

    // ----- FC tail (fp32): fc1 -> bufB, then fused fc2+encode -> out -----
    fc_kernel<<<101, B, 0, stream>>>(bufA, fw1, fb1, bufB, 640, 100, 1);
    fc2_encode_kernel<<<11, B, 0, stream>>>(bufB, fw2, fb2, perm[11], diag[11], out);
}

// Round 10
// 321.731 us; speedup vs baseline: 1.5536x; 1.5536x over previous
//
#include <hip/hip_runtime.h>

// ---------------------------------------------------------------------------
// StochasticKeyNet:  decode_i(relu(encode_i(y))) == relu(y)  (diag > 0), so
// only the first decode and last encode survive.  Convs = implicit-GEMM f16
// MFMA (16x16x32), activations packed [ci/8][h][w][n][ci%8] f16, direct
// per-wave global loads (no LDS; R7/R8 LDS staging failed: 1 block/CU can't
// hide the barrier drain).  R9 = R6 config + generic NSPLIT (l2 x2, tail x4)
// + fused decode/pack.
// ---------------------------------------------------------------------------

#define B 128
#define ZPAD 2048   // leading zero page (elements) in each packed act buffer

typedef _Float16 f16_t;
typedef __attribute__((ext_vector_type(8))) _Float16 f16x8;
typedef __attribute__((ext_vector_type(4))) _Float16 f16x4;
typedef __attribute__((ext_vector_type(4))) float f32x4;

// ---------------- fused decode + f16 pack -----------------------------------
// v[perm[j]] = x[j]/diag[j]; target row i=perm[j] < 3072 lands in packed
// layout [p][n][ci%8] (single cg for Ci=3); row 3072 is the t row.
// Slots ci%8 in 3..7 are pre-zeroed by pack_weights_kernel.

__global__ void decode_pack_kernel(const float* __restrict__ x, const int* __restrict__ perm,
                                   const float* __restrict__ diag,
                                   f16_t* __restrict__ xout, float* __restrict__ tout) {
    int row = blockIdx.x * 2 + (threadIdx.x >> 7);
    if (row >= 3073) return;
    int n = threadIdx.x & 127;
    int i = perm[row];
    float val = x[(size_t)row * B + n] / diag[row];
    if (i < 3072) {
        int c = i >> 10, p = i & 1023;
        xout[ZPAD + p * 1024 + n * 8 + c] = (f16_t)val;
    } else {
        tout[n] = val;
    }
}

// ---------------- FC tail ----------------------------------------------------

__global__ void fc_kernel(const float* __restrict__ v, const float* __restrict__ w,
                          const float* __restrict__ b, float* __restrict__ y,
                          int K, int R, int do_relu) {
    int r = blockIdx.x;
    int n = threadIdx.x;
    float t = v[(size_t)K * B + n];
    float val;
    if (r == R) {
        val = t;
    } else {
        float a0 = 0.f, a1 = 0.f, a2 = 0.f, a3 = 0.f;
        float a4 = 0.f, a5 = 0.f, a6 = 0.f, a7 = 0.f;
        const float* wr = w + (size_t)r * K;
        int k = 0;
        for (; k + 8 <= K; k += 8) {
            float4 w0 = *(const float4*)(wr + k);
            float4 w1 = *(const float4*)(wr + k + 4);
            float x0 = v[(size_t)(k + 0) * B + n];
            float x1 = v[(size_t)(k + 1) * B + n];
            float x2 = v[(size_t)(k + 2) * B + n];
            float x3 = v[(size_t)(k + 3) * B + n];
            float x4 = v[(size_t)(k + 4) * B + n];
            float x5 = v[(size_t)(k + 5) * B + n];
            float x6 = v[(size_t)(k + 6) * B + n];
            float x7 = v[(size_t)(k + 7) * B + n];
            a0 = fmaf(w0.x, x0, a0);
            a1 = fmaf(w0.y, x1, a1);
            a2 = fmaf(w0.z, x2, a2);
            a3 = fmaf(w0.w, x3, a3);
            a4 = fmaf(w1.x, x4, a4);
            a5 = fmaf(w1.y, x5, a5);
            a6 = fmaf(w1.z, x6, a6);
            a7 = fmaf(w1.w, x7, a7);
        }
        for (; k < K; ++k)
            a0 = fmaf(wr[k], v[(size_t)k * B + n], a0);
        val = b[r] * t + ((a0 + a1) + (a2 + a3)) + ((a4 + a5) + (a6 + a7));
    }
    if (do_relu) val = fmaxf(val, 0.f);
    y[(size_t)r * B + n] = val;
}

// fc2 + final encode fused
__global__ void fc2_encode_kernel(const float* __restrict__ v, const float* __restrict__ w,
                                  const float* __restrict__ b, const int* __restrict__ perm,
                                  const float* __restrict__ diag, float* __restrict__ out) {
    int jrow = blockIdx.x;          // 0..10
    int n = threadIdx.x;            // 0..127
    int r = perm[jrow];
    float d = diag[jrow];
    float t = v[100 * B + n];
    float val;
    if (r == 10) {
        val = t;
    } else {
        float a0 = 0.f, a1 = 0.f, a2 = 0.f, a3 = 0.f;
        const float* wr = w + (size_t)r * 100;
        for (int k = 0; k < 100; k += 4) {
            float4 w4 = *(const float4*)(wr + k);
            a0 = fmaf(w4.x, v[(size_t)(k + 0) * B + n], a0);
            a1 = fmaf(w4.y, v[(size_t)(k + 1) * B + n], a1);
            a2 = fmaf(w4.z, v[(size_t)(k + 2) * B + n], a2);
            a3 = fmaf(w4.w, v[(size_t)(k + 3) * B + n], a3);
        }
        val = b[r] * t + (a0 + a1) + (a2 + a3);
    }
    out[(size_t)jrow * B + n] = d * val;
}

// ---------------- prep: pack all conv weights/biases to f16 -----------------
// Also zero-inits: both buffers' zero pages + the full l0 packed-input region
// of x8a (so decode_pack only writes ci slots 0..2).

struct WArgs {
    const float* w[9]; const float* b[9];
    int Ci[9], Co[9], KS[9], Cp[9], NCG[9];
    int woff[10]; int boff[10];
};

__global__ void pack_weights_kernel(WArgs A, f16_t* __restrict__ wp, float* __restrict__ bp,
                                    f16_t* __restrict__ x8a, f16_t* __restrict__ x8b) {
    int idx = blockIdx.x * 256 + threadIdx.x;
    if (idx < ZPAD + 1048576) x8a[idx] = (f16_t)0.f;   // zero page + l0 input region
    if (idx < ZPAD) x8b[idx] = (f16_t)0.f;
    if (idx < A.boff[9]) {
        int l = 0;
        while (idx >= A.boff[l + 1]) ++l;
        int co = idx - A.boff[l];
        bp[idx] = (co < A.Co[l]) ? A.b[l][co] : 0.f;
    }
    if (idx >= A.woff[9]) return;
    int l = 0;
    while (idx >= A.woff[l + 1]) ++l;
    int e = idx - A.woff[l];
    int j = e & 7;
    int t1 = e >> 3;
    int Cp = A.Cp[l];
    int co = t1 % Cp;
    int gg = t1 / Cp;
    int ncg = A.NCG[l];
    int tap = gg / ncg, cg = gg - tap * ncg;
    int ks = A.KS[l];
    int kh = tap / ks, kw = tap - kh * ks;
    int ci = cg * 8 + j;
    float val = 0.f;
    if (co < A.Co[l] && tap < ks * ks && ci < A.Ci[l])
        val = A.w[l][(((size_t)co * A.Ci[l] + ci) * ks + kh) * ks + kw];
    wp[idx] = (f16_t)val;
}

// ---------------- direct-load MFMA conv (R6 structure, generic NSPLIT) ------
// CBW>1: block = CBW co-waves on one pixel (B dedupes in L1).
// CBW=1: 1-wave blocks; grid carries CB co-groups.
// NSPLIT: waves take 1/NSPLIT of the batch (NS = 8/NSPLIT) -> more blocks
// for grid-starved layers.  XCD-contiguous swizzle: xcd = bid&7.
// K-loop: PF=2 register pipeline; per-quad (cg,hi,wi) tracked branchlessly.

template <int KS, int NS, int NSPLIT, int CBW, bool F32OUT>
__global__ __launch_bounds__(64 * CBW) void conv_mfma_kernel(
    const f16_t* __restrict__ xin, const float* __restrict__ t_in,
    const f16_t* __restrict__ wp, const float* __restrict__ bp,
    f16_t* __restrict__ xout, float* __restrict__ t_out, float* __restrict__ f32out,
    int Hi, int Wi, int Wo_log2, int HWo,
    int stride, int pad, int NCG, int nchunk, int KGr, int Co, int Co_pad,
    int PB8, int CB)
{
    constexpr int PF = 2;
    constexpr int MS = 4;
    const int wave = threadIdx.x >> 6;
    const int lane = threadIdx.x & 63;
    const int q = lane >> 4;       // quad -> k-group within chunk, C rows q*4..q*4+3
    const int r = lane & 15;       // A: co row / B,C: column n (mod 16)

    const int gb = blockIdx.x;
    const int xcd = gb & 7;
    int j = gb >> 3;
    int nh = 0, cog, p;
    if (NSPLIT > 1) { nh = j % NSPLIT; j /= NSPLIT; }
    if (CBW > 1) {
        cog = wave;
        p = xcd * PB8 + j;
    } else {
        cog = j % CB;
        p = xcd * PB8 + j / CB;
    }
    const int co0 = cog * 64;
    const int ncol0 = nh * (NS * 16);
    const int ncol8 = ncol0 * 8;

    const int ho = p >> Wo_log2;
    const int wo = p & ((1 << Wo_log2) - 1);
    const f16_t* xdata = xin + ZPAD;

    float tv[NS];
#pragma unroll
    for (int ns = 0; ns < NS; ++ns) tv[ns] = t_in[ncol0 + ns * 16 + r];

    f32x4 acc[MS][NS];
#pragma unroll
    for (int ms = 0; ms < MS; ++ms) {
        float4 b4 = *(const float4*)(bp + co0 + ms * 16 + q * 4);
#pragma unroll
        for (int ns = 0; ns < NS; ++ns) {
            acc[ms][ns][0] = b4.x * tv[ns];
            acc[ms][ns][1] = b4.y * tv[ns];
            acc[ms][ns][2] = b4.z * tv[ns];
            acc[ms][ns][3] = b4.w * tv[ns];
        }
    }

    const int hb = ho * stride - pad, wb = wo * stride - pad;
    const int HiWi = Hi * Wi;
    const int HiWi4 = 4 * HiWi;
    const int NCGHW = NCG * HiWi;
    const int wend = wb + KS;

    int g = q, cg = q, hi = hb, wi = wb, cgHW;
    {
        while (cg >= NCG) { cg -= NCG; ++wi; if (wi == wend) { wi = wb; ++hi; } }
        cgHW = cg * HiWi;
    }

    f16x8 bf[PF][NS], af[PF][MS];

    auto advance = [&]() {
        g += 4; cg += 4; cgHW += HiWi4;
        if (NCG >= 4) {            // at most one wrap
            int c2 = cg - NCG;
            bool wrap = c2 >= 0;
            int wn = wi + 1;
            bool ww = wrap & (wn == wend);
            cg   = wrap ? c2 : cg;
            cgHW = wrap ? cgHW - NCGHW : cgHW;
            wi   = wrap ? (ww ? wb : wn) : wi;
            hi   = ww ? hi + 1 : hi;
        } else {
            while (cg >= NCG) { cg -= NCG; cgHW -= NCGHW; ++wi; if (wi == wend) { wi = wb; ++hi; } }
        }
    };
    auto loadB = [&](f16x8* b) {
        bool v = (g < KGr) & ((unsigned)hi < (unsigned)Hi) & ((unsigned)wi < (unsigned)Wi);
        int boff = (cgHW + hi * Wi + wi) << 10;        // *128*8 elements
        const f16_t* bb = xdata + (v ? boff : -ZPAD) + ncol8 + r * 8;
#pragma unroll
        for (int ns = 0; ns < NS; ++ns) b[ns] = *(const f16x8*)(bb + ns * 128);
    };
    auto loadA = [&](f16x8* a, int c) {
        int ac = c < nchunk ? c : nchunk - 1;          // clamp phantom chunks
        const f16_t* ap = wp + (((ac * 4 + q) * Co_pad) + co0 + r) * 8;
#pragma unroll
        for (int ms = 0; ms < MS; ++ms) a[ms] = *(const f16x8*)(ap + ms * 128);
    };
    auto domfma = [&](f16x8* a, f16x8* b) {
#pragma unroll
        for (int ms = 0; ms < MS; ++ms)
#pragma unroll
            for (int ns = 0; ns < NS; ++ns)
                acc[ms][ns] = __builtin_amdgcn_mfma_f32_16x16x32_f16(a[ms], b[ns], acc[ms][ns], 0, 0, 0);
    };

    // phantom chunks (c >= nchunk) have g >= KGr -> B reads zero page -> no-op
#pragma unroll
    for (int pf = 0; pf < PF; ++pf) { loadB(bf[pf]); loadA(af[pf], pf); advance(); }
    const int nck = ((nchunk + PF - 1) / PF) * PF;
    for (int c = 0; c < nck; c += PF) {
#pragma unroll
        for (int pf = 0; pf < PF; ++pf) {
            domfma(af[pf], bf[pf]);
            loadB(bf[pf]); loadA(af[pf], c + PF + pf); advance();
        }
    }

    if (!F32OUT) {
#pragma unroll
        for (int ms = 0; ms < MS; ++ms) {
            int cob = co0 + ms * 16 + q * 4;            // 4 consecutive co rows
            if (cob < Co) {
                int off0 = ((cob >> 3) * HWo + p) * 1024 + (cob & 7) + ncol8 + r * 8;
#pragma unroll
                for (int ns = 0; ns < NS; ++ns) {
                    f16x4 h;
                    h[0] = (f16_t)fmaxf(acc[ms][ns][0], 0.f);
                    h[1] = (f16_t)fmaxf(acc[ms][ns][1], 0.f);
                    h[2] = (f16_t)fmaxf(acc[ms][ns][2], 0.f);
                    h[3] = (f16_t)fmaxf(acc[ms][ns][3], 0.f);
                    *(f16x4*)(xout + ZPAD + off0 + ns * 128) = h;
                }
            }
        }
        if (gb == 0) {
            for (int i = threadIdx.x; i < B; i += 64 * CBW)
                t_out[i] = fmaxf(t_in[i], 0.f);
        }
    } else {
#pragma unroll
        for (int ms = 0; ms < MS; ++ms)
#pragma unroll
            for (int ns = 0; ns < NS; ++ns)
#pragma unroll
                for (int e = 0; e < 4; ++e) {
                    int co = co0 + ms * 16 + q * 4 + e;
                    if (co < Co)
                        f32out[((size_t)co * HWo + p) * B + ncol0 + ns * 16 + r] =
                            fmaxf(acc[ms][ns][e], 0.f);
                }
        if (gb == 0) {
            for (int i = threadIdx.x; i < B; i += 64 * CBW)
                f32out[(size_t)Co * HWo * B + i] = fmaxf(t_in[i], 0.f);
        }
    }
}

// ---------------------------------------------------------------------------

extern "C" void kernel_launch(void* const* d_in, const int* in_sizes, int n_in,
                              void* d_out, int out_size, void* d_ws, size_t ws_size,
                              hipStream_t stream) {
    const float* x0 = (const float*)d_in[0];
    const int*   perm[12];
    const float* diag[12];
    for (int i = 0; i < 12; ++i) {
        perm[i] = (const int*)d_in[1 + 2 * i];
        diag[i] = (const float*)d_in[2 + 2 * i];
    }
    const float* wts[9];
    const float* bia[9];
    for (int j = 0; j < 9; ++j) {
        wts[j] = (const float*)d_in[25 + 2 * j];
        bia[j] = (const float*)d_in[26 + 2 * j];
    }
    const float* fw1 = (const float*)d_in[43];
    const float* fb1 = (const float*)d_in[44];
    const float* fw2 = (const float*)d_in[45];
    const float* fb2 = (const float*)d_in[46];
    float* out = (float*)d_out;

    // ----- layer tables -----
    static const int CiA[9]  = {3, 96, 96, 96, 192, 192, 192, 192, 192};
    static const int CoA[9]  = {96, 96, 96, 192, 192, 192, 192, 192, 10};
    static const int KSA[9]  = {3, 3, 3, 3, 3, 3, 3, 1, 1};
    static const int CpA[9]  = {128, 128, 128, 192, 192, 192, 192, 192, 64};
    static const int NCGA[9] = {1, 12, 12, 12, 24, 24, 24, 24, 24};
    static const int KGRA[9] = {9, 108, 108, 108, 216, 216, 216, 24, 24};
    static const int NCHK[9] = {3, 27, 27, 27, 54, 54, 54, 6, 6};
    static const int HiA[9]  = {32, 32, 32, 16, 16, 16, 8, 8, 8};
    static const int WoL[9]  = {5, 5, 4, 4, 4, 3, 3, 3, 3};
    static const int HWoA[9] = {1024, 1024, 256, 256, 256, 64, 64, 64, 64};
    static const int STA[9]  = {1, 1, 2, 1, 1, 2, 1, 1, 1};
    static const int PDA[9]  = {1, 1, 1, 1, 1, 1, 1, 0, 0};

    // ----- workspace layout -----
    char* wsb = (char*)d_ws;
    const size_t BUF_F32  = 1574912;
    const size_t X8_BYTES = (size_t)(ZPAD + 12 * 1024 * 1024) * 2;
    float* bufA = (float*)wsb;
    float* bufB = (float*)(wsb + BUF_F32);
    f16_t* x8a  = (f16_t*)(wsb + 2 * BUF_F32);
    f16_t* x8b  = (f16_t*)(wsb + 2 * BUF_F32 + X8_BYTES);
    f16_t* wpb  = (f16_t*)(wsb + 2 * BUF_F32 + 2 * X8_BYTES);
    const size_t WP_BYTES = 2888704;
    float* bpb  = (float*)(wsb + 2 * BUF_F32 + 2 * X8_BYTES + WP_BYTES);
    float* t0   = (float*)((char*)bpb + 8192);
    float* t1   = t0 + 256;

    // ----- pack weights/bias + zero-init (every call) -----
    WArgs WA;
    int wo = 0, bo = 0;
    for (int l = 0; l < 9; ++l) {
        WA.w[l] = wts[l]; WA.b[l] = bia[l];
        WA.Ci[l] = CiA[l]; WA.Co[l] = CoA[l]; WA.KS[l] = KSA[l];
        WA.Cp[l] = CpA[l]; WA.NCG[l] = NCGA[l];
        WA.woff[l] = wo; wo += NCHK[l] * 4 * CpA[l] * 8;
        WA.boff[l] = bo; bo += CpA[l];
    }
    WA.woff[9] = wo; WA.boff[9] = bo;
    pack_weights_kernel<<<(wo + 255) / 256, 256, 0, stream>>>(WA, wpb, bpb, x8a, x8b);

    // ----- fused decode + pack to f16 -----
    decode_pack_kernel<<<(3073 + 1) / 2, 256, 0, stream>>>(x0, perm[0], diag[0], x8a, t0);

    // ----- conv stack -----
    f16_t* xin = x8a; f16_t* xout = x8b;
    float* tin = t0;  float* tout = t1;
    for (int l = 0; l < 9; ++l) {
        const int PB8 = HWoA[l] / 8;
        const int CB = CpA[l] / 64;
        const f16_t* wpl = wpb + WA.woff[l];
        const float* bpl = bpb + WA.boff[l];
        if (l <= 1) {           // heavy 32x32 layers: 2-wave blocks, full batch
            conv_mfma_kernel<3, 8, 1, 2, false><<<8 * PB8, 128, 0, stream>>>(
                xin, tin, wpl, bpl, xout, tout, nullptr,
                HiA[l], HiA[l], WoL[l], HWoA[l], STA[l], PDA[l],
                NCGA[l], NCHK[l], KGRA[l], CoA[l], CpA[l], PB8, CB);
        } else if (l == 2) {    // stride-2: 2-wave blocks + n-split (grid 512)
            conv_mfma_kernel<3, 4, 2, 2, false><<<8 * PB8 * 2, 128, 0, stream>>>(
                xin, tin, wpl, bpl, xout, tout, nullptr,
                HiA[l], HiA[l], WoL[l], HWoA[l], STA[l], PDA[l],
                NCGA[l], NCHK[l], KGRA[l], CoA[l], CpA[l], PB8, CB);
        } else if (l <= 4) {    // 16x16 Cp=192: 3-wave blocks, full batch
            conv_mfma_kernel<3, 8, 1, 3, false><<<8 * PB8, 192, 0, stream>>>(
                xin, tin, wpl, bpl, xout, tout, nullptr,
                HiA[l], HiA[l], WoL[l], HWoA[l], STA[l], PDA[l],
                NCGA[l], NCHK[l], KGRA[l], CoA[l], CpA[l], PB8, CB);
        } else if (l <= 6) {    // 8x8 KS=3 tail: 1-wave, n-split x4
            conv_mfma_kernel<3, 2, 4, 1, false><<<8 * PB8 * CB * 4, 64, 0, stream>>>(
                xin, tin, wpl, bpl, xout, tout, nullptr,
                HiA[l], HiA[l], WoL[l], HWoA[l], STA[l], PDA[l],
                NCGA[l], NCHK[l], KGRA[l], CoA[l], CpA[l], PB8, CB);
        } else if (l == 7) {    // 1x1: 1-wave, n-split x4
            conv_mfma_kernel<1, 2, 4, 1, false><<<8 * PB8 * CB * 4, 64, 0, stream>>>(
                xin, tin, wpl, bpl, xout, tout, nullptr,
                HiA[l], HiA[l], WoL[l], HWoA[l], STA[l], PDA[l],
                NCGA[l], NCHK[l], KGRA[l], CoA[l], CpA[l], PB8, CB);
        } else {                // last conv, fp32 out, n-split x4
            conv_mfma_kernel<1, 2, 4, 1, true><<<8 * PB8 * CB * 4, 64, 0, stream>>>(
                xin, tin, wpl, bpl, nullptr, nullptr, bufA,
                HiA[l], HiA[l], WoL[l], HWoA[l], STA[l], PDA[l],
                NCGA[l], NCHK[l], KGRA[l], CoA[l], CpA[l], PB8, CB);
        }
        f16_t* xt = xin; xin = xout; xout = xt;
        float* tt = tin; tin = tout; tout = tt;
    }

    // ----- FC tail (fp32): fc1 -> bufB, then fused fc2+encode -> out -----
    fc_kernel<<<101, B, 0, stream>>>(bufA, fw1, fb1, bufB, 640, 100, 1);
    fc2_encode_kernel<<<11, B, 0, stream>>>(bufB, fw2, fb2, perm[11], diag[11], out);
}